// Round 1
// baseline (1710.025 us; speedup 1.0000x reference)
//
#include <hip/hip_runtime.h>

#define NTOK (32*4096)           // 131072 tokens
#define WQ_FLOATS (5*144*32)     // fused qkv weights
#define BQ_FLOATS (5*144)

// ---------- setup: fold agg_W/agg_b through in_proj into W_qkv/b_qkv ----------
// W_qkv[a][r][d] = sum_e in_proj_w[r][e]*agg_W[a][e][d];  q-rows (r<48) pre-scaled by 1/sqrt(24)
__global__ void setup_wqkv(const float* __restrict__ aggW,   // (5,48,32)
                           const float* __restrict__ aggB,   // (5,48)
                           const float* __restrict__ ipw,    // (144,48)
                           const float* __restrict__ ipb,    // (144,)
                           float* __restrict__ Wq,           // (5,144,32)
                           float* __restrict__ bq)           // (5,144)
{
    int t = blockIdx.x*256 + threadIdx.x;
    if (t >= 5*144) return;
    int a = t / 144;
    int r = t - a*144;
    float scale = (r < 48) ? 0.20412414523193154f : 1.0f;    // 1/sqrt(24)
    const float* wrow = ipw + r*48;
    float bacc = ipb[r];
    for (int e = 0; e < 48; ++e) bacc += wrow[e]*aggB[a*48 + e];
    bq[t] = bacc*scale;
    for (int d = 0; d < 32; ++d) {
        float acc = 0.f;
        for (int e = 0; e < 48; ++e) acc += wrow[e]*aggW[(a*48 + e)*32 + d];
        Wq[t*32 + d] = acc*scale;
    }
}

// ---------- main fused kernel ----------
// Gather decode: row a2 of token m is flat row g=5m+a2 of the transposed proj:
//   b = g/20480, a = (g>>12)%5, n = g&4095;  x chunk = x[(b*4096+n)*256 + a*32 .. +32]
__device__ __forceinline__ void rowinfo(unsigned m, int a2, unsigned& xo, unsigned& wa)
{
    unsigned g = 5u*m + (unsigned)a2;
    unsigned u = g >> 12;                 // < 160
    unsigned b = (u * 52429u) >> 18;      // u/5
    unsigned a = u - 5u*b;                // u%5
    xo = (((b << 12) | (g & 4095u)) << 8) + (a << 5);
    wa = a;
}

__device__ __forceinline__ void load_x32(const float* __restrict__ x, unsigned xo, float xr[32])
{
    const float4* xv = reinterpret_cast<const float4*>(x + xo);
#pragma unroll
    for (int i = 0; i < 8; ++i) {
        float4 v = xv[i];
        xr[4*i+0] = v.x; xr[4*i+1] = v.y; xr[4*i+2] = v.z; xr[4*i+3] = v.w;
    }
}

// Compute 48 fused-qkv rows [ROWBASE, ROWBASE+48) for this thread's gathered weight
// index wa. wa is wave-uniform except when the wave straddles a 4096-row page
// (wa in {w0, w0+1 mod 5}); rare 2nd pass recomputes + selects. Weight addresses are
// readfirstlane-uniform -> scalar loads feeding v_fma.
template<int ROWBASE>
__device__ __forceinline__ void qkv_rows48(const float* __restrict__ Wq,
                                           const float* __restrict__ bq,
                                           unsigned wa, const float xr[32], float t[48])
{
    unsigned w0 = (unsigned)__builtin_amdgcn_readfirstlane((int)wa);
    int npass = __all((int)(wa == w0)) ? 1 : 2;
#pragma unroll 1
    for (int p = 0; p < npass; ++p) {
        unsigned w = p ? (w0 == 4u ? 0u : w0 + 1u) : w0;
        const float* __restrict__ Wb = Wq + (w*144u + (unsigned)ROWBASE)*32u;
        const float* __restrict__ Bb = bq + (w*144u + (unsigned)ROWBASE);
#pragma unroll
        for (int e = 0; e < 48; ++e) {
            float acc = Bb[e];
#pragma unroll
            for (int d = 0; d < 32; ++d)
                acc = fmaf(Wb[e*32 + d], xr[d], acc);
            float sel;
            if (p == 0) sel = acc;
            else        sel = (wa == w) ? acc : t[e];
            t[e] = sel;
        }
    }
}

__global__ __launch_bounds__(256, 1) void fused_main(
    const float* __restrict__ x,     // (32,4096,256)
    const float* __restrict__ Wq,    // (5,144,32) fused
    const float* __restrict__ bq,    // (5,144)
    const float* __restrict__ outw,  // (48,48)
    const float* __restrict__ outb,  // (48,)
    const float* __restrict__ exw,   // (272,96)
    const float* __restrict__ exb,   // (272,)
    float* __restrict__ out)         // (32,4096,512)
{
    const unsigned m = blockIdx.x*blockDim.x + threadIdx.x;
    if (m >= NTOK) return;

    // per-thread scores/attn scratch in LDS (runtime-ak indexable); stride 51 -> conflict-free
    __shared__ float sc_lds[256][51];
    float* sc = sc_lds[threadIdx.x];

    // ---------------- P1: Q[5][48] ----------------
    float Q[5][48];
#pragma unroll
    for (int j = 0; j < 5; ++j)
#pragma unroll
        for (int e = 0; e < 48; ++e) Q[j][e] = 0.f;

#pragma unroll 1
    for (int aq = 0; aq < 5; ++aq) {
        unsigned xo, wa; rowinfo(m, aq, xo, wa);
        float xr[32]; load_x32(x, xo, xr);
        float t[48];
        qkv_rows48<0>(Wq, bq, wa, xr, t);
#pragma unroll
        for (int j = 0; j < 5; ++j)
#pragma unroll
            for (int e = 0; e < 48; ++e)
                Q[j][e] = (aq == j) ? t[e] : Q[j][e];
    }

    // ---------------- P2: K stream -> scores (to LDS) ----------------
#pragma unroll 1
    for (int ak = 0; ak < 5; ++ak) {
        unsigned xo, wa; rowinfo(m, ak, xo, wa);
        float xr[32]; load_x32(x, xo, xr);
        float t[48];
        qkv_rows48<48>(Wq, bq, wa, xr, t);
        float s0[5] = {0,0,0,0,0}, s1[5] = {0,0,0,0,0};
#pragma unroll
        for (int e = 0; e < 24; ++e)
#pragma unroll
            for (int j = 0; j < 5; ++j) s0[j] = fmaf(Q[j][e], t[e], s0[j]);
#pragma unroll
        for (int e = 24; e < 48; ++e)
#pragma unroll
            for (int j = 0; j < 5; ++j) s1[j] = fmaf(Q[j][e], t[e], s1[j]);
#pragma unroll
        for (int j = 0; j < 5; ++j) {
            sc[j*5 + ak]      = s0[j];   // h=0
            sc[25 + j*5 + ak] = s1[j];   // h=1
        }
    }

    // ---------------- softmax (per-thread, no barrier) ----------------
#pragma unroll
    for (int h = 0; h < 2; ++h)
#pragma unroll
        for (int j = 0; j < 5; ++j) {
            float* p = sc + h*25 + j*5;
            float v0 = p[0], v1 = p[1], v2 = p[2], v3 = p[3], v4 = p[4];
            float mx = fmaxf(fmaxf(fmaxf(v0, v1), fmaxf(v2, v3)), v4);
            v0 = __expf(v0 - mx); v1 = __expf(v1 - mx); v2 = __expf(v2 - mx);
            v3 = __expf(v3 - mx); v4 = __expf(v4 - mx);
            float inv = 1.0f / (v0 + v1 + v2 + v3 + v4);
            p[0] = v0*inv; p[1] = v1*inv; p[2] = v2*inv; p[3] = v3*inv; p[4] = v4*inv;
        }

    // ---------------- P4: V stream -> o[5][48] ----------------
    float o[5][48];
#pragma unroll
    for (int j = 0; j < 5; ++j)
#pragma unroll
        for (int e = 0; e < 48; ++e) o[j][e] = 0.f;

#pragma unroll 1
    for (int ak = 0; ak < 5; ++ak) {
        unsigned xo, wa; rowinfo(m, ak, xo, wa);
        float xr[32]; load_x32(x, xo, xr);
        float t[48];
        qkv_rows48<96>(Wq, bq, wa, xr, t);
        float a0[5], a1[5];
#pragma unroll
        for (int j = 0; j < 5; ++j) { a0[j] = sc[j*5 + ak]; a1[j] = sc[25 + j*5 + ak]; }
#pragma unroll
        for (int e = 0; e < 24; ++e)
#pragma unroll
            for (int j = 0; j < 5; ++j) o[j][e] = fmaf(a0[j], t[e], o[j][e]);
#pragma unroll
        for (int e = 24; e < 48; ++e)
#pragma unroll
            for (int j = 0; j < 5; ++j) o[j][e] = fmaf(a1[j], t[e], o[j][e]);
    }

    // ---------------- P5: out-proj + store cols [0,240) ----------------
    const size_t obase = (size_t)m * 512u;
#pragma unroll 1
    for (int aq = 0; aq < 5; ++aq) {
        float orow[48];
#pragma unroll
        for (int f = 0; f < 48; ++f) orow[f] = o[0][f];
#pragma unroll
        for (int j = 1; j < 5; ++j)
#pragma unroll
            for (int f = 0; f < 48; ++f) orow[f] = (aq == j) ? o[j][f] : orow[f];

#pragma unroll 1
        for (int ec = 0; ec < 3; ++ec) {
            float acc[16];
#pragma unroll
            for (int e2 = 0; e2 < 16; ++e2) {
                float a = outb[ec*16 + e2];
#pragma unroll
                for (int f = 0; f < 48; ++f)
                    a = fmaf(outw[(ec*16 + e2)*48 + f], orow[f], a);
                acc[e2] = a;
            }
            float4* dst = reinterpret_cast<float4*>(out + obase + aq*48 + ec*16);
#pragma unroll
            for (int q = 0; q < 4; ++q)
                dst[q] = make_float4(acc[4*q+0], acc[4*q+1], acc[4*q+2], acc[4*q+3]);
        }
    }

    // ---------------- P6: extra path, cols [240,512) ----------------
    float xe[96];
    {
        const float4* xv = reinterpret_cast<const float4*>(x + (size_t)m*256u + 160u);
#pragma unroll
        for (int i = 0; i < 24; ++i) {
            float4 v = xv[i];
            xe[4*i+0] = v.x; xe[4*i+1] = v.y; xe[4*i+2] = v.z; xe[4*i+3] = v.w;
        }
    }
#pragma unroll 1
    for (int c = 0; c < 17; ++c) {
        float acc[16];
#pragma unroll
        for (int j = 0; j < 16; ++j) {
            float a = exb[c*16 + j];
#pragma unroll
            for (int d = 0; d < 96; ++d)
                a = fmaf(exw[(c*16 + j)*96 + d], xe[d], a);
            acc[j] = a;
        }
        float4* dst = reinterpret_cast<float4*>(out + obase + 240u + c*16);
#pragma unroll
        for (int q = 0; q < 4; ++q)
            dst[q] = make_float4(acc[4*q+0], acc[4*q+1], acc[4*q+2], acc[4*q+3]);
    }
}

// ---------------- launch ----------------
extern "C" void kernel_launch(void* const* d_in, const int* in_sizes, int n_in,
                              void* d_out, int out_size, void* d_ws, size_t ws_size,
                              hipStream_t stream)
{
    const float* x    = (const float*)d_in[0];
    const float* aggW = (const float*)d_in[1];
    const float* aggB = (const float*)d_in[2];
    const float* ipw  = (const float*)d_in[3];
    const float* ipb  = (const float*)d_in[4];
    const float* outw = (const float*)d_in[5];
    const float* outb = (const float*)d_in[6];
    const float* exw  = (const float*)d_in[7];
    const float* exb  = (const float*)d_in[8];
    float* out = (float*)d_out;

    float* Wq = (float*)d_ws;                 // 23040 floats
    float* bq = Wq + WQ_FLOATS;               // 720 floats (95 KB total, well under ws)

    setup_wqkv<<<dim3(3), dim3(256), 0, stream>>>(aggW, aggB, ipw, ipb, Wq, bq);
    fused_main<<<dim3(NTOK/256), dim3(256), 0, stream>>>(x, Wq, bq, outw, outb, exw, exb, out);
}

// Round 2
// 1482.671 us; speedup vs baseline: 1.1533x; 1.1533x over previous
//
#include <hip/hip_runtime.h>

#define NTOK (32*4096)           // 131072 tokens
#define WQ_FLOATS (5*144*32)     // fused qkv weights

// ---------- setup: fold agg_W/agg_b through in_proj into W_qkv/b_qkv ----------
// W_qkv[a][r][d] = sum_e in_proj_w[r][e]*agg_W[a][e][d];  q-rows (r<48) pre-scaled by 1/sqrt(24)
__global__ void setup_wqkv(const float* __restrict__ aggW,   // (5,48,32)
                           const float* __restrict__ aggB,   // (5,48)
                           const float* __restrict__ ipw,    // (144,48)
                           const float* __restrict__ ipb,    // (144,)
                           float* __restrict__ Wq,           // (5,144,32)
                           float* __restrict__ bq)           // (5,144)
{
    int t = blockIdx.x*256 + threadIdx.x;
    if (t >= 5*144) return;
    int a = t / 144;
    int r = t - a*144;
    float scale = (r < 48) ? 0.20412414523193154f : 1.0f;    // 1/sqrt(24)
    const float* wrow = ipw + r*48;
    float bacc = ipb[r];
    for (int e = 0; e < 48; ++e) bacc += wrow[e]*aggB[a*48 + e];
    bq[t] = bacc*scale;
    for (int d = 0; d < 32; ++d) {
        float acc = 0.f;
        for (int e = 0; e < 48; ++e) acc += wrow[e]*aggW[(a*48 + e)*32 + d];
        Wq[t*32 + d] = acc*scale;
    }
}

__device__ __forceinline__ void load_xchunk(const float* __restrict__ p, float xr[32])
{
    const float4* xv = reinterpret_cast<const float4*>(p);
#pragma unroll
    for (int i = 0; i < 8; ++i) {
        float4 t = xv[i];
        xr[4*i+0] = t.x; xr[4*i+1] = t.y; xr[4*i+2] = t.z; xr[4*i+3] = t.w;
    }
}

// ---------- main attention kernel: one thread = one (token, row) ----------
// Row a2 of token m is flat row g = 5m+a2 with (b = (g>>12)/5, a = (g>>12)%5, n = g&4095);
// x chunk = x[(b*4096+n)*256 + a*32 .. +32).  A wave handles 12 tokens in lanes 0..59:
// g = 5*m_base + lane, so the 5 rows of a token occupy 5 adjacent lanes and share `a`
// (except rare 4096-crossing waves -> 2-pass select). k/v exchanged by ds_bpermute
// rotations inside each 5-lane group; no LDS, no barriers.
__global__ __launch_bounds__(256) void attn_main(
    const float* __restrict__ x,     // (32,4096,256)
    const float* __restrict__ Wq,    // (5,144,32) fused
    const float* __restrict__ bq,    // (5,144)
    const float* __restrict__ outw,  // (48,48)
    const float* __restrict__ outb,  // (48,)
    float* __restrict__ out)         // (32,4096,512), cols [0,240)
{
    const int lane = (int)(threadIdx.x & 63u);
    if (lane >= 60) return;
    const int wv = (int)(threadIdx.x >> 6u);
    const unsigned m_base = (blockIdx.x*4u + (unsigned)wv)*12u;
    const unsigned tok5 = (unsigned)lane / 5u;
    const unsigned aq   = (unsigned)lane - tok5*5u;
    const unsigned m = m_base + tok5;
    if (m >= NTOK) return;

    const unsigned g  = 5u*m_base + (unsigned)lane;     // == 5m + aq
    const unsigned u  = g >> 12;                        // < 160
    const unsigned bb = (u*52429u) >> 18;               // u/5
    const unsigned a  = u - 5u*bb;                      // u%5 -> weight index
    const float* xp = x + ((((bb<<12) | (g & 4095u)) << 8) + (a<<5));

    const unsigned w0 = (unsigned)__builtin_amdgcn_readfirstlane((int)a);
    const int npass = __all((int)(a == w0)) ? 1 : 2;

    // ---------- q,k for my row ----------
    float q[48], k[48];
    {
        float xr[32]; load_xchunk(xp, xr);
#pragma unroll 1
        for (int p = 0; p < npass; ++p) {
            const unsigned w = p ? (w0 == 4u ? 0u : w0 + 1u) : w0;
            const float* __restrict__ Wb = Wq + w*4608u;   // 144*32
            const float* __restrict__ Bb = bq + w*144u;
            const bool keep = (p == 0) || (a == w);
#pragma unroll
            for (int e = 0; e < 48; ++e) {
                float acc = Bb[e];
#pragma unroll
                for (int d = 0; d < 32; ++d) acc = fmaf(Wb[e*32 + d], xr[d], acc);
                q[e] = keep ? acc : q[e];
            }
#pragma unroll
            for (int e = 0; e < 48; ++e) {
                float acc = Bb[48 + e];
#pragma unroll
                for (int d = 0; d < 32; ++d) acc = fmaf(Wb[(48 + e)*32 + d], xr[d], acc);
                k[e] = keep ? acc : k[e];
            }
        }
    }

    // ---------- scores via k-rotation; s[r] = q(my row) . k(row (aq+r)%5) ----------
    const int base4 = (lane - (int)aq)*4;   // group base lane * 4 (bpermute byte addr)
    float s0[5], s1[5];
    {
        float a0 = 0.f, a1 = 0.f;
#pragma unroll
        for (int e = 0; e < 24; ++e) a0 = fmaf(q[e], k[e], a0);
#pragma unroll
        for (int e = 24; e < 48; ++e) a1 = fmaf(q[e], k[e], a1);
        s0[0] = a0; s1[0] = a1;
    }
#pragma unroll
    for (int r = 1; r < 5; ++r) {
        int sl = (int)aq + r; sl = (sl >= 5) ? sl - 5 : sl;
        const int addr = base4 + sl*4;
        float a0 = 0.f, a1 = 0.f;
#pragma unroll
        for (int e = 0; e < 48; ++e) {
            float kr = __int_as_float(__builtin_amdgcn_ds_bpermute(addr, __float_as_int(k[e])));
            if (e < 24) a0 = fmaf(q[e], kr, a0);
            else        a1 = fmaf(q[e], kr, a1);
        }
        s0[r] = a0; s1[r] = a1;
    }

    // ---------- softmax over r (scale already folded into q weights) ----------
    float p0[5], p1[5];
    {
        float mx = fmaxf(fmaxf(fmaxf(s0[0], s0[1]), fmaxf(s0[2], s0[3])), s0[4]);
        float e0 = __expf(s0[0]-mx), e1 = __expf(s0[1]-mx), e2 = __expf(s0[2]-mx),
              e3 = __expf(s0[3]-mx), e4 = __expf(s0[4]-mx);
        float inv = 1.0f/(e0+e1+e2+e3+e4);
        p0[0]=e0*inv; p0[1]=e1*inv; p0[2]=e2*inv; p0[3]=e3*inv; p0[4]=e4*inv;
    }
    {
        float mx = fmaxf(fmaxf(fmaxf(s1[0], s1[1]), fmaxf(s1[2], s1[3])), s1[4]);
        float e0 = __expf(s1[0]-mx), e1 = __expf(s1[1]-mx), e2 = __expf(s1[2]-mx),
              e3 = __expf(s1[3]-mx), e4 = __expf(s1[4]-mx);
        float inv = 1.0f/(e0+e1+e2+e3+e4);
        p1[0]=e0*inv; p1[1]=e1*inv; p1[2]=e2*inv; p1[3]=e3*inv; p1[4]=e4*inv;
    }

    // ---------- v for my row (x reloads hit L1) ----------
    float v[48];
    {
        float xr[32]; load_xchunk(xp, xr);
#pragma unroll 1
        for (int p = 0; p < npass; ++p) {
            const unsigned w = p ? (w0 == 4u ? 0u : w0 + 1u) : w0;
            const float* __restrict__ Wb = Wq + w*4608u + 96*32;
            const float* __restrict__ Bb = bq + w*144u + 96;
            const bool keep = (p == 0) || (a == w);
#pragma unroll
            for (int e = 0; e < 48; ++e) {
                float acc = Bb[e];
#pragma unroll
                for (int d = 0; d < 32; ++d) acc = fmaf(Wb[e*32 + d], xr[d], acc);
                v[e] = keep ? acc : v[e];
            }
        }
    }

    // ---------- PV via v-rotation (same rotation index pairing as scores) ----------
    float o[48];
#pragma unroll
    for (int e = 0; e < 48; ++e) o[e] = ((e < 24) ? p0[0] : p1[0]) * v[e];
#pragma unroll
    for (int r = 1; r < 5; ++r) {
        int sl = (int)aq + r; sl = (sl >= 5) ? sl - 5 : sl;
        const int addr = base4 + sl*4;
#pragma unroll
        for (int e = 0; e < 48; ++e) {
            float vr = __int_as_float(__builtin_amdgcn_ds_bpermute(addr, __float_as_int(v[e])));
            o[e] = fmaf((e < 24) ? p0[r] : p1[r], vr, o[e]);
        }
    }

    // ---------- out-proj (48x48) + store my row's 48 cols ----------
    float* __restrict__ dst = out + (size_t)m*512u + aq*48u;
#pragma unroll 1
    for (int e8 = 0; e8 < 6; ++e8) {
        float acc[8];
#pragma unroll
        for (int j = 0; j < 8; ++j) {
            float s = outb[e8*8 + j];
            const float* __restrict__ wrow = outw + (e8*8 + j)*48;
#pragma unroll
            for (int f = 0; f < 48; ++f) s = fmaf(wrow[f], o[f], s);
            acc[j] = s;
        }
        float4* d4 = reinterpret_cast<float4*>(dst + e8*8);
        d4[0] = make_float4(acc[0], acc[1], acc[2], acc[3]);
        d4[1] = make_float4(acc[4], acc[5], acc[6], acc[7]);
    }
}

// ---------- extra path: cols [240,512), one thread = one token ----------
__global__ __launch_bounds__(256) void extra_kernel(
    const float* __restrict__ x,     // (32,4096,256)
    const float* __restrict__ exw,   // (272,96)
    const float* __restrict__ exb,   // (272,)
    float* __restrict__ out)         // cols [240,512)
{
    const unsigned m = blockIdx.x*256u + threadIdx.x;
    if (m >= NTOK) return;

    float xe[96];
    {
        const float4* xv = reinterpret_cast<const float4*>(x + (size_t)m*256u + 160u);
#pragma unroll
        for (int i = 0; i < 24; ++i) {
            float4 t = xv[i];
            xe[4*i+0] = t.x; xe[4*i+1] = t.y; xe[4*i+2] = t.z; xe[4*i+3] = t.w;
        }
    }

    float* __restrict__ dst = out + (size_t)m*512u + 240u;
#pragma unroll 1
    for (int c = 0; c < 17; ++c) {
        float acc[16];
#pragma unroll
        for (int j = 0; j < 16; ++j) {
            float s = exb[c*16 + j];
            const float* __restrict__ wrow = exw + (c*16 + j)*96;
#pragma unroll
            for (int d = 0; d < 96; ++d) s = fmaf(wrow[d], xe[d], s);
            acc[j] = s;
        }
        float4* d4 = reinterpret_cast<float4*>(dst + c*16);
#pragma unroll
        for (int t = 0; t < 4; ++t)
            d4[t] = make_float4(acc[4*t+0], acc[4*t+1], acc[4*t+2], acc[4*t+3]);
    }
}

// ---------------- launch ----------------
extern "C" void kernel_launch(void* const* d_in, const int* in_sizes, int n_in,
                              void* d_out, int out_size, void* d_ws, size_t ws_size,
                              hipStream_t stream)
{
    const float* x    = (const float*)d_in[0];
    const float* aggW = (const float*)d_in[1];
    const float* aggB = (const float*)d_in[2];
    const float* ipw  = (const float*)d_in[3];
    const float* ipb  = (const float*)d_in[4];
    const float* outw = (const float*)d_in[5];
    const float* outb = (const float*)d_in[6];
    const float* exw  = (const float*)d_in[7];
    const float* exb  = (const float*)d_in[8];
    float* out = (float*)d_out;

    float* Wq = (float*)d_ws;                 // 23040 floats
    float* bq = Wq + WQ_FLOATS;               // 720 floats

    setup_wqkv<<<dim3(3), dim3(256), 0, stream>>>(aggW, aggB, ipw, ipb, Wq, bq);
    // 48 tokens per 256-thread block (12 per wave, lanes 0..59)
    attn_main<<<dim3((NTOK + 47)/48), dim3(256), 0, stream>>>(x, Wq, bq, outw, outb, out);
    extra_kernel<<<dim3(NTOK/256), dim3(256), 0, stream>>>(x, exw, exb, out);
}